// Round 7
// baseline (3091.448 us; speedup 1.0000x reference)
//
#include <hip/hip_runtime.h>

// LSTM B=1024, T=256, H=256, fp32-accurate via bf16x3-split MFMA. v7.
// Grid 256 = 32 rowgroups (32 rows) x 8 colgroups (32 hcols). Block 512 thr
// = 8 waves (2/SIMD, 256-reg cap). Wave owns one 16-gatecol MFMA col-tile,
// gatecol = ho*4 + g  ->  a quad (4 lanes) = 4 gates of one hcol.
// Weights: per lane 8 Ksteps x 3 bf16-splits x short8 = 96 VGPR, used directly
// as MFMA B-operands (register-resident by construction).
// Per step: [stage: 7 waves each fetch one partner's 32-col fp32 slice
// (coherent agent-scope), split to bf16x3 in regs, write swizzled LDS planes]
// -> sync -> [MFMA: 2 row-tiles x 8 K x 6 split-terms into f32x4 acc]
// -> sync -> [phase B in-registers: +x*Wx+b, activations, quad_perm gather,
// c/h update, write fp32 h global + own-slice bf16 planes] -> sync -> flag.
// Split-term error ~2^-24 rel; k-permutation identical for A and B frags so
// any k-order mismatch with HW cancels in the accumulation.

#define Bsz   1024
#define Tt    256
#define Hh    256
#define NCLS  10
#define RGR   32
#define NRG   32
#define NCG   8
#define NTHR  512
#define HSZ   ((size_t)Bsz * Hh)

typedef float  f32x4 __attribute__((ext_vector_type(4)));
typedef short  s16x8 __attribute__((ext_vector_type(8)));
typedef unsigned long long u64;
typedef unsigned int u32;

__device__ __forceinline__ unsigned short f2bf(float f) {   // RNE f32->bf16
    u32 u = __builtin_bit_cast(u32, f);
    return (unsigned short)((u + 0x7FFFu + ((u >> 16) & 1u)) >> 16);
}
__device__ __forceinline__ float bf2f(unsigned short b) {
    u32 u = ((u32)b) << 16;
    return __builtin_bit_cast(float, u);
}

template<int CTRL>
__device__ __forceinline__ float quadf(float v) {           // quad_perm bcast
    return __builtin_bit_cast(float,
        __builtin_amdgcn_update_dpp(0, __builtin_bit_cast(int, v),
                                    CTRL, 0xF, 0xF, true));
}

__device__ __forceinline__ float fast_tanh(float v) {
    const float e = __expf(-2.0f * fabsf(v));
    const float t = (1.0f - e) * __builtin_amdgcn_rcpf(1.0f + e);
    return copysignf(t, v);
}

__device__ __forceinline__ u64 coh_load64(const u64* p) {
    return __hip_atomic_load((u64*)p, __ATOMIC_RELAXED, __HIP_MEMORY_SCOPE_AGENT);
}
__device__ __forceinline__ unsigned coh_load32(const unsigned* p) {
    return __hip_atomic_load((unsigned*)p, __ATOMIC_RELAXED, __HIP_MEMORY_SCOPE_AGENT);
}
__device__ __forceinline__ void coh_storef(float* p, float v) {
    __hip_atomic_store(p, v, __ATOMIC_RELAXED, __HIP_MEMORY_SCOPE_AGENT);
}

extern "C" __global__ void __launch_bounds__(NTHR, 2)
lstm_mfma(const float* __restrict__ x,
          const float* __restrict__ W_gx, const float* __restrict__ W_gh, const float* __restrict__ b_g,
          const float* __restrict__ W_ix, const float* __restrict__ W_ih, const float* __restrict__ b_i,
          const float* __restrict__ W_fx, const float* __restrict__ W_fh, const float* __restrict__ b_f,
          const float* __restrict__ W_ox, const float* __restrict__ W_oh, const float* __restrict__ b_o,
          const float* __restrict__ W_ph, const float* __restrict__ b_p,
          float* __restrict__ out, float* __restrict__ hbuf, unsigned* __restrict__ fcnt)
{
    // 3 bf16 planes of h(t): [plane s][row 0..31][k 0..255], 512 B/row,
    // byte addr XOR-swizzled with ((row&7)<<4). 48 KB total.
    __shared__ __align__(16) char planes[3 * 16384];

    const int tid  = threadIdx.x;
    const int lane = tid & 63;
    const int wv   = tid >> 6;            // col-tile owner (0..7)
    const int rg   = blockIdx.x >> 3;
    const int cg   = blockIdx.x & 7;
    const int r0   = rg * RGR;

    // lane roles inside the wave's 16-col tile (gc = ho*4 + g):
    const int g    = lane & 3;            // gate 0:g 1:i 2:f 3:o
    const int dho  = (lane & 15) >> 2;    // 0..3
    const int ho   = wv * 4 + dho;        // hcol offset in block (0..31)
    const int jcol = cg * 32 + ho;        // global hcol
    const int bkg  = lane >> 4;           // k-group for A/B frags
    const int arow = lane & 15;           // A-frag row within tile

    // ---- B-frags: 8 Ksteps x 3 splits, short8 each = 96 VGPR, pinned ----
    const float* __restrict__ Wg = (g == 0) ? W_gh : (g == 1) ? W_ih
                                 : (g == 2) ? W_fh : W_oh;
    s16x8 bw[8][3];
    #pragma unroll
    for (int ks = 0; ks < 8; ++ks) {
        s16x8 b1v, b2v, b3v;
        #pragma unroll
        for (int e = 0; e < 8; ++e) {
            const int k = ks * 32 + bkg * 8 + e;
            const float w = Wg[(size_t)k * Hh + jcol];
            const unsigned short c1 = f2bf(w);
            const float r1 = w - bf2f(c1);
            const unsigned short c2 = f2bf(r1);
            const float r2 = r1 - bf2f(c2);
            const unsigned short c3 = f2bf(r2);
            b1v[e] = (short)c1; b2v[e] = (short)c2; b3v[e] = (short)c3;
        }
        bw[ks][0] = b1v; bw[ks][1] = b2v; bw[ks][2] = b3v;
    }

    // phase-B constants; reference bias swap preserved (f uses b_o, o uses b_f)
    const float* __restrict__ Wx[4] = {W_gx, W_ix, W_fx, W_ox};
    const float* __restrict__ Bb[4] = {b_g, b_i, b_o, b_f};
    const float wxv = Wx[g][jcol];
    const float bbv = Bb[g][jcol];
    float c_st[2][4];
    #pragma unroll
    for (int rt = 0; rt < 2; ++rt)
        #pragma unroll
        for (int r = 0; r < 4; ++r) c_st[rt][r] = 0.0f;

    unsigned* fbase = fcnt + rg * NCG;

    // zero planes (h0 = 0)
    for (int i = tid; i < 3 * 16384 / 4; i += NTHR) ((u32*)planes)[i] = 0u;
    __syncthreads();

    // staging role: lane -> (row = lane>>1, 16-float chunk = lane&1)
    const int srow = lane >> 1;
    const int sc0base = (lane & 1) * 16;

    for (int t = 0; t < Tt; ++t) {
        const float* hcur = hbuf + ((t & 1) ? HSZ : 0);
        float*       hnxt = hbuf + ((t & 1) ? 0 : HSZ);

        // x_t for my 8 states (issues early, L1 broadcast)
        float xv[2][4];
        #pragma unroll
        for (int rt = 0; rt < 2; ++rt)
            #pragma unroll
            for (int r = 0; r < 4; ++r)
                xv[rt][r] = x[(size_t)(r0 + rt * 16 + 4 * bkg + r) * Tt + t];

        // ---- stage one partner's 32-col fp32 slice -> bf16x3 planes ----
        if (wv < 7) {
            const int pcg = wv + (wv >= cg ? 1 : 0);
            if (t > 0) {
                const unsigned* fp = fbase + pcg;
                while (coh_load32(fp) < (unsigned)t) __builtin_amdgcn_s_sleep(1);
            }
            const int sc0 = pcg * 32 + sc0base;          // float col
            const u64* src = (const u64*)(hcur + (size_t)(r0 + srow) * Hh + sc0);
            const int swz = ((srow & 7) << 4);
            #pragma unroll
            for (int i = 0; i < 8; ++i) {
                const u64 v = coh_load64(src + i);
                const float lo = __builtin_bit_cast(float, (u32)v);
                const float hi = __builtin_bit_cast(float, (u32)(v >> 32));
                const unsigned short l1 = f2bf(lo);
                const float lr1 = lo - bf2f(l1);
                const unsigned short l2 = f2bf(lr1);
                const unsigned short l3 = f2bf(lr1 - bf2f(l2));
                const unsigned short h1 = f2bf(hi);
                const float hr1 = hi - bf2f(h1);
                const unsigned short h2 = f2bf(hr1);
                const unsigned short h3 = f2bf(hr1 - bf2f(h2));
                const int cb = (sc0 + 2 * i) * 2;        // byte col in row
                const int off = srow * 512 + (cb ^ swz);
                *(u32*)(planes + off)             = (u32)l1 | ((u32)h1 << 16);
                *(u32*)(planes + 16384 + off)     = (u32)l2 | ((u32)h2 << 16);
                *(u32*)(planes + 32768 + off)     = (u32)l3 | ((u32)h3 << 16);
            }
        }
        __syncthreads();                                  // planes = split(h(t))

        // ---- MFMA: acc[rt] += sum_ks 6 split-terms ----
        f32x4 acc[2];
        acc[0] = (f32x4){0.f, 0.f, 0.f, 0.f};
        acc[1] = (f32x4){0.f, 0.f, 0.f, 0.f};
        #pragma unroll
        for (int ks = 0; ks < 8; ++ks) {
            const int cb = (ks * 32 + bkg * 8) * 2;      // 16B-aligned byte col
            #pragma unroll
            for (int rt = 0; rt < 2; ++rt) {
                const int row = rt * 16 + arow;
                const int off = row * 512 + (cb ^ ((row & 7) << 4));
                const s16x8 a1 = *reinterpret_cast<const s16x8*>(planes + off);
                const s16x8 a2 = *reinterpret_cast<const s16x8*>(planes + 16384 + off);
                const s16x8 a3 = *reinterpret_cast<const s16x8*>(planes + 32768 + off);
                acc[rt] = __builtin_amdgcn_mfma_f32_16x16x32_bf16(a1, bw[ks][0], acc[rt], 0, 0, 0);
                acc[rt] = __builtin_amdgcn_mfma_f32_16x16x32_bf16(a2, bw[ks][0], acc[rt], 0, 0, 0);
                acc[rt] = __builtin_amdgcn_mfma_f32_16x16x32_bf16(a1, bw[ks][1], acc[rt], 0, 0, 0);
                acc[rt] = __builtin_amdgcn_mfma_f32_16x16x32_bf16(a2, bw[ks][1], acc[rt], 0, 0, 0);
                acc[rt] = __builtin_amdgcn_mfma_f32_16x16x32_bf16(a3, bw[ks][0], acc[rt], 0, 0, 0);
                acc[rt] = __builtin_amdgcn_mfma_f32_16x16x32_bf16(a1, bw[ks][2], acc[rt], 0, 0, 0);
            }
        }
        __syncthreads();                                  // all plane reads done

        // ---- phase B: in-register activations + state update ----
        #pragma unroll
        for (int rt = 0; rt < 2; ++rt) {
            #pragma unroll
            for (int r = 0; r < 4; ++r) {
                const float pre = acc[rt][r] + fmaf(xv[rt][r], wxv, bbv);
                // my gate's activation (exact-form tanh for g==0)
                const float vin = (g == 0) ? 2.0f * pre : pre;
                const float e   = __expf(-fabsf(vin));
                const float rc  = __builtin_amdgcn_rcpf(1.0f + e);
                const float sig = (vin >= 0.0f) ? rc : 1.0f - rc;
                const float th  = copysignf((1.0f - e) * rc, pre);
                const float act = (g == 0) ? th : sig;
                // gather 4 gates within the quad
                const float gv = quadf<0x00>(act);
                const float iv = quadf<0x55>(act);
                const float fv = quadf<0xAA>(act);
                const float ov = quadf<0xFF>(act);
                float& cc = c_st[rt][r];
                cc = fmaf(gv, iv, cc * fv);
                const float hv = fast_tanh(cc) * ov;
                const int row = rt * 16 + 4 * bkg + r;
                // split h for next step's planes
                const unsigned short s1 = f2bf(hv);
                const float r1 = hv - bf2f(s1);
                const unsigned short s2 = f2bf(r1);
                const unsigned short s3 = f2bf(r1 - bf2f(s2));
                if (g == 3) {
                    coh_storef(&hnxt[(size_t)(r0 + row) * Hh + jcol], hv);
                } else {
                    const unsigned short sv = (g == 0) ? s1 : (g == 1) ? s2 : s3;
                    const int off = row * 512 + ((jcol * 2) ^ ((row & 7) << 4));
                    *(unsigned short*)(planes + g * 16384 + off) = sv;
                }
            }
        }
        __syncthreads();                                  // drains LDS + vmcnt
        if (tid == 0)
            __hip_atomic_store(fbase + cg, (unsigned)(t + 1),
                               __ATOMIC_RELEASE, __HIP_MEMORY_SCOPE_AGENT);
    }

    // ---- classifier (cg==0): out = h_T @ W_ph + b_p; h_T fp32 in buffer 0 ----
    if (cg == 0) {
        for (int c = 1; c < NCG; ++c)
            while (coh_load32(fbase + c) < (unsigned)Tt) __builtin_amdgcn_s_sleep(1);
        // stage h_T tile (32 x 256 fp32 = 32 KB) linearly into planes area
        u64* hl = (u64*)planes;
        const u64* hT = (const u64*)hbuf + (size_t)r0 * (Hh / 2);
        #pragma unroll
        for (int i = 0; i < 8; ++i)
            hl[tid + i * NTHR] = coh_load64(hT + tid + i * NTHR);
        __syncthreads();
        const float* hf = (const float*)planes;
        for (int idx = tid; idx < RGR * NCLS; idx += NTHR) {
            const int row = idx / NCLS;
            const int cc  = idx - row * NCLS;
            float a = b_p[cc];
            for (int k = 0; k < Hh; ++k)
                a = fmaf(hf[row * Hh + k], W_ph[k * NCLS + cc], a);
            out[(size_t)(r0 + row) * NCLS + cc] = a;
        }
    }
}

extern "C" void kernel_launch(void* const* d_in, const int* in_sizes, int n_in,
                              void* d_out, int out_size, void* d_ws, size_t ws_size,
                              hipStream_t stream) {
    const float* x    = (const float*)d_in[0];
    const float* W_gx = (const float*)d_in[1];
    const float* W_gh = (const float*)d_in[2];
    const float* b_g  = (const float*)d_in[3];
    const float* W_ix = (const float*)d_in[4];
    const float* W_ih = (const float*)d_in[5];
    const float* b_i  = (const float*)d_in[6];
    const float* W_fx = (const float*)d_in[7];
    const float* W_fh = (const float*)d_in[8];
    const float* b_f  = (const float*)d_in[9];
    const float* W_ox = (const float*)d_in[10];
    const float* W_oh = (const float*)d_in[11];
    const float* b_o  = (const float*)d_in[12];
    const float* W_ph = (const float*)d_in[13];
    const float* b_p  = (const float*)d_in[14];
    float* out = (float*)d_out;

    float*    hbuf = (float*)d_ws;                       // 2 x 1 MB ping-pong
    unsigned* fcnt = (unsigned*)((char*)d_ws + 2 * HSZ * sizeof(float));
    const size_t clear_bytes = 2 * HSZ * sizeof(float) + NRG * NCG * sizeof(unsigned);

    hipMemsetAsync(d_ws, 0, clear_bytes, stream);        // h0 = 0 + flags = 0

    lstm_mfma<<<dim3(NRG * NCG), dim3(NTHR), 0, stream>>>(
        x, W_gx, W_gh, b_g, W_ix, W_ih, b_i, W_fx, W_fh, b_f,
        W_ox, W_oh, b_o, W_ph, b_p, out, hbuf, fcnt);
}

// Round 8
// 2122.327 us; speedup vs baseline: 1.4566x; 1.4566x over previous
//
#include <hip/hip_runtime.h>

// LSTM B=1024, T=256, H=256, fp32-accurate via bf16x2-split (3-term) MFMA. v8.
// Grid 256 = 32 rowgroups (32 rows) x 8 colgroups (32 hcols); bid = cg*32+rg
// so a rowgroup's 8 partner blocks share an XCD (perf only). Block 512 thr =
// 8 waves = 4 col-subtiles (cs) x 2 k-halves (kh); wave = 32 rows x 32 gatecols
// x K=128 using v_mfma_f32_32x32x16_bf16 (A row=lane&31, k=(lane>>5)*8+e;
// D col=lane&31, row=(reg&3)+8*(reg>>2)+4*(lane>>5) [m74]).
// A-planes in LDS in FRAGMENT ORDER [kstep][lane][16B] -> every ds access
// (stage write, A read, part write/read) is lane-stride-1 = conflict-free.
// Weights: 2 bf16 splits x 8 ksteps x short8 = 64 VGPR/lane, MFMA B-operands.
// 3 split terms (a1b1, a2b1, a1b2); dropped a2b2 ~ 2^-18 rel.
// h exchanged as packed u32 (bf16 hi/lo pair) via agent-scope coherent ops;
// per-block monotonic flags; 3 syncthreads/step.

#define Bsz   1024
#define Tt    256
#define Hh    256
#define NCLS  10
#define RGR   32
#define NRG   32
#define NCG   8
#define NTHR  512
#define HSZ   ((size_t)Bsz * Hh)      // u32 elems per hpack buffer

typedef float f32x16 __attribute__((ext_vector_type(16)));
typedef short s16x8  __attribute__((ext_vector_type(8)));
typedef unsigned long long u64;
typedef unsigned int u32;

// LDS layout (bytes)
#define PLANES 0                      // 2 planes x 16 KB, frag order
#define POFF   16384
#define PART   32768                  // 4 cs x 4 KB, frag order
#define HOWN   49152                  // 32 rows x 36 u32 (pad) = 4608 B
#define SMEMB  (49152 + 4608)

__device__ __forceinline__ unsigned short f2bf(float f) {   // RNE f32->bf16
    u32 u = __builtin_bit_cast(u32, f);
    return (unsigned short)((u + 0x7FFFu + ((u >> 16) & 1u)) >> 16);
}
__device__ __forceinline__ float bf2f(unsigned short b) {
    u32 u = ((u32)b) << 16;
    return __builtin_bit_cast(float, u);
}
template<int CTRL>
__device__ __forceinline__ float quadf(float v) {           // quad_perm bcast
    return __builtin_bit_cast(float,
        __builtin_amdgcn_update_dpp(0, __builtin_bit_cast(int, v),
                                    CTRL, 0xF, 0xF, true));
}
__device__ __forceinline__ float fast_tanh(float v) {
    const float e = __expf(-2.0f * fabsf(v));
    const float t = (1.0f - e) * __builtin_amdgcn_rcpf(1.0f + e);
    return copysignf(t, v);
}
__device__ __forceinline__ u64 coh_load64(const u64* p) {
    return __hip_atomic_load((u64*)p, __ATOMIC_RELAXED, __HIP_MEMORY_SCOPE_AGENT);
}
__device__ __forceinline__ unsigned coh_load32(const unsigned* p) {
    return __hip_atomic_load((unsigned*)p, __ATOMIC_RELAXED, __HIP_MEMORY_SCOPE_AGENT);
}
__device__ __forceinline__ void coh_store32(u32* p, u32 v) {
    __hip_atomic_store(p, v, __ATOMIC_RELAXED, __HIP_MEMORY_SCOPE_AGENT);
}

extern "C" __global__ void __launch_bounds__(NTHR, 2)
lstm_v8(const float* __restrict__ x,
        const float* __restrict__ W_gx, const float* __restrict__ W_gh, const float* __restrict__ b_g,
        const float* __restrict__ W_ix, const float* __restrict__ W_ih, const float* __restrict__ b_i,
        const float* __restrict__ W_fx, const float* __restrict__ W_fh, const float* __restrict__ b_f,
        const float* __restrict__ W_ox, const float* __restrict__ W_oh, const float* __restrict__ b_o,
        const float* __restrict__ W_ph, const float* __restrict__ b_p,
        float* __restrict__ out, u32* __restrict__ hpack, unsigned* __restrict__ fcnt)
{
    __shared__ __align__(16) char smem[SMEMB];

    const int tid  = threadIdx.x;
    const int lane = tid & 63;
    const int wv   = tid >> 6;
    const int rg   = blockIdx.x & 31;      // partners (all cg) share XCD rg%8
    const int cg   = blockIdx.x >> 5;
    const int r0   = rg * RGR;
    const int cs   = wv & 3;               // col-subtile (32 gatecols)
    const int kh   = wv >> 2;              // k-half (K=128)

    // ---- B-frags: gate/hcol per lane; 8 ksteps x 2 splits = 64 VGPR ----
    const int gate   = lane & 3;           // gc = hcol*4 + gate
    const int hcol_l = cs * 8 + ((lane & 31) >> 2);   // block-local 0..31
    const int hcol_g = cg * 32 + hcol_l;
    const int kb     = kh * 128 + (lane >> 5) * 8;
    const float* __restrict__ Wg =
        (gate == 0) ? W_gh : (gate == 1) ? W_ih : (gate == 2) ? W_fh : W_oh;
    s16x8 bw1[8], bw2[8];
    #pragma unroll
    for (int ks = 0; ks < 8; ++ks) {
        s16x8 v1, v2;
        #pragma unroll
        for (int e = 0; e < 8; ++e) {
            const float w = Wg[(size_t)(kb + ks * 16 + e) * Hh + hcol_g];
            const unsigned short c1 = f2bf(w);
            const unsigned short c2 = f2bf(w - bf2f(c1));
            v1[e] = (short)c1; v2[e] = (short)c2;
        }
        bw1[ks] = v1; bw2[ks] = v2;
    }

    // reference bias swap preserved: f-gate uses b_o, o-gate uses b_f
    const float wx = ((gate == 0) ? W_gx : (gate == 1) ? W_ix : (gate == 2) ? W_fx : W_ox)[hcol_g];
    const float bb = ((gate == 0) ? b_g  : (gate == 1) ? b_i  : (gate == 2) ? b_o  : b_f )[hcol_g];
    float c_st[16];
    #pragma unroll
    for (int r = 0; r < 16; ++r) c_st[r] = 0.0f;

    unsigned* fbase = fcnt + rg * NCG;

    // stage role: wave wv stages slice spcg (wv==7 -> own, from HOWN)
    const int spcg   = (cg + 1 + wv) & 7;
    const int srow   = lane & 31;
    const int skc    = lane >> 5;          // 16-col half of the 32-col slice
    const int skstep = spcg * 2 + skc;

    u32* hown = (u32*)(smem + HOWN);
    for (int i = tid; i < 32 * 36; i += NTHR) hown[i] = 0u;
    __syncthreads();

    for (int t = 0; t < Tt; ++t) {
        const u32* hcur = hpack + ((t & 1) ? HSZ : 0);
        u32*       hnxt = hpack + ((t & 1) ? 0 : HSZ);

        // ---- stage one 32-col slice into frag-ordered planes ----
        u32 v[16];
        if (wv < 7) {
            if (t > 0)
                while (coh_load32(fbase + spcg) < (unsigned)t) __builtin_amdgcn_s_sleep(1);
            const u64* src = (const u64*)(hcur + (size_t)(r0 + srow) * Hh + spcg * 32 + skc * 16);
            #pragma unroll
            for (int i = 0; i < 8; ++i) {
                const u64 q = coh_load64(src + i);
                v[2 * i]     = (u32)q;
                v[2 * i + 1] = (u32)(q >> 32);
            }
        } else {
            const u32* hp = hown + srow * 36 + skc * 16;
            #pragma unroll
            for (int i = 0; i < 4; ++i) {
                const uint4 q = *(const uint4*)(hp + 4 * i);
                v[4 * i] = q.x; v[4 * i + 1] = q.y; v[4 * i + 2] = q.z; v[4 * i + 3] = q.w;
            }
        }
        #pragma unroll
        for (int half = 0; half < 2; ++half) {
            const u32* s = v + half * 8;
            uint4 dlo, dhi;
            dlo.x = (s[0] & 0xffffu) | (s[1] << 16);
            dlo.y = (s[2] & 0xffffu) | (s[3] << 16);
            dlo.z = (s[4] & 0xffffu) | (s[5] << 16);
            dlo.w = (s[6] & 0xffffu) | (s[7] << 16);
            dhi.x = (s[0] >> 16) | (s[1] & 0xffff0000u);
            dhi.y = (s[2] >> 16) | (s[3] & 0xffff0000u);
            dhi.z = (s[4] >> 16) | (s[5] & 0xffff0000u);
            dhi.w = (s[6] >> 16) | (s[7] & 0xffff0000u);
            char* base = smem + PLANES + skstep * 1024 + (srow + 32 * half) * 16;
            *(uint4*)base          = dlo;
            *(uint4*)(base + POFF) = dhi;
        }
        __syncthreads();                               // planes = split(h(t))

        // ---- MFMA: 8 ksteps x 3 split-terms, stride-1 frag reads ----
        f32x16 acc = {0.f};
        #pragma unroll
        for (int ks = 0; ks < 8; ++ks) {
            const char* ab = smem + PLANES + ((kh * 8 + ks) << 10) + (lane << 4);
            const s16x8 a1 = *(const s16x8*)ab;
            const s16x8 a2 = *(const s16x8*)(ab + POFF);
            acc = __builtin_amdgcn_mfma_f32_32x32x16_bf16(a1, bw1[ks], acc, 0, 0, 0);
            acc = __builtin_amdgcn_mfma_f32_32x32x16_bf16(a2, bw1[ks], acc, 0, 0, 0);
            acc = __builtin_amdgcn_mfma_f32_32x32x16_bf16(a1, bw2[ks], acc, 0, 0, 0);
        }
        if (kh == 1) {                                 // publish k-half partial
            float* pb = (float*)(smem + PART) + cs * 1024 + lane * 4;
            #pragma unroll
            for (int i = 0; i < 4; ++i) {
                float4 w4;
                w4.x = acc[4 * i]; w4.y = acc[4 * i + 1];
                w4.z = acc[4 * i + 2]; w4.w = acc[4 * i + 3];
                *(float4*)(pb + i * 256) = w4;
            }
        }
        __syncthreads();

        // ---- phase B (kh==0 waves): reduce, activate, update, publish ----
        if (kh == 0) {
            const float* pb = (const float*)(smem + PART) + cs * 1024 + lane * 4;
            #pragma unroll
            for (int i = 0; i < 4; ++i) {
                const float4 r4 = *(const float4*)(pb + i * 256);
                acc[4 * i] += r4.x; acc[4 * i + 1] += r4.y;
                acc[4 * i + 2] += r4.z; acc[4 * i + 3] += r4.w;
            }
            float xv[16];
            #pragma unroll
            for (int r = 0; r < 16; ++r) {
                const int row = (r & 3) + 8 * (r >> 2) + 4 * (lane >> 5);
                xv[r] = x[(size_t)(r0 + row) * Tt + t];
            }
            #pragma unroll
            for (int r = 0; r < 16; ++r) {
                const int row = (r & 3) + 8 * (r >> 2) + 4 * (lane >> 5);
                const float pre = acc[r] + fmaf(xv[r], wx, bb);
                const float vin = (gate == 0) ? 2.0f * pre : pre;
                const float e   = __expf(-fabsf(vin));
                const float rc  = __builtin_amdgcn_rcpf(1.0f + e);
                const float sig = (vin >= 0.0f) ? rc : 1.0f - rc;
                const float th  = copysignf((1.0f - e) * rc, pre);
                const float act = (gate == 0) ? th : sig;
                const float gv = quadf<0x00>(act);
                const float iv = quadf<0x55>(act);
                const float fv = quadf<0xAA>(act);
                const float ov = quadf<0xFF>(act);
                c_st[r] = fmaf(gv, iv, c_st[r] * fv);
                const float hv = fast_tanh(c_st[r]) * ov;
                if (gate == 0) {
                    const unsigned short h1 = f2bf(hv);
                    const unsigned short h2 = f2bf(hv - bf2f(h1));
                    const u32 packed = (u32)h1 | ((u32)h2 << 16);
                    coh_store32(&hnxt[(size_t)(r0 + row) * Hh + hcol_g], packed);
                    hown[row * 36 + hcol_l] = packed;
                }
            }
        }
        __syncthreads();                               // drains vmcnt + LDS
        if (tid == 0)
            __hip_atomic_store(fbase + cg, (unsigned)(t + 1),
                               __ATOMIC_RELEASE, __HIP_MEMORY_SCOPE_AGENT);
    }

    // ---- classifier (cg==0): out = h_T @ W_ph + b_p ----
    if (cg == 0) {
        for (int c = 1; c < NCG; ++c)
            while (coh_load32(fbase + c) < (unsigned)Tt) __builtin_amdgcn_s_sleep(1);
        u32* tile = (u32*)(smem + PLANES);             // [32][256] packed h_T
        const u64* src = (const u64*)(hpack + (size_t)r0 * Hh);   // t=255 -> buf0
        for (int i = tid; i < 32 * 128; i += NTHR) {
            const u64 q = coh_load64(src + i);
            tile[2 * i] = (u32)q; tile[2 * i + 1] = (u32)(q >> 32);
        }
        __syncthreads();
        for (int idx = tid; idx < RGR * NCLS; idx += NTHR) {
            const int row = idx / NCLS;
            const int cc  = idx - row * NCLS;
            float a = b_p[cc];
            for (int k = 0; k < Hh; ++k) {
                const u32 p = tile[row * Hh + k];
                const float h = bf2f((unsigned short)p) + bf2f((unsigned short)(p >> 16));
                a = fmaf(h, W_ph[k * NCLS + cc], a);
            }
            out[(size_t)(r0 + row) * NCLS + cc] = a;
        }
    }
}

extern "C" void kernel_launch(void* const* d_in, const int* in_sizes, int n_in,
                              void* d_out, int out_size, void* d_ws, size_t ws_size,
                              hipStream_t stream) {
    const float* x    = (const float*)d_in[0];
    const float* W_gx = (const float*)d_in[1];
    const float* W_gh = (const float*)d_in[2];
    const float* b_g  = (const float*)d_in[3];
    const float* W_ix = (const float*)d_in[4];
    const float* W_ih = (const float*)d_in[5];
    const float* b_i  = (const float*)d_in[6];
    const float* W_fx = (const float*)d_in[7];
    const float* W_fh = (const float*)d_in[8];
    const float* b_f  = (const float*)d_in[9];
    const float* W_ox = (const float*)d_in[10];
    const float* W_oh = (const float*)d_in[11];
    const float* b_o  = (const float*)d_in[12];
    const float* W_ph = (const float*)d_in[13];
    const float* b_p  = (const float*)d_in[14];
    float* out = (float*)d_out;

    u32*      hpack = (u32*)d_ws;                        // 2 x 1 MB ping-pong
    unsigned* fcnt  = (unsigned*)((char*)d_ws + 2 * HSZ * sizeof(u32));
    const size_t clear_bytes = 2 * HSZ * sizeof(u32) + NRG * NCG * sizeof(unsigned);

    hipMemsetAsync(d_ws, 0, clear_bytes, stream);        // h0 = 0 + flags = 0

    lstm_v8<<<dim3(NRG * NCG), dim3(NTHR), 0, stream>>>(
        x, W_gx, W_gh, b_g, W_ix, W_ih, b_i, W_fx, W_fh, b_f,
        W_ox, W_oh, b_o, W_ph, b_p, out, hpack, fcnt);
}